// Round 5
// baseline (172.942 us; speedup 1.0000x reference)
//
#include <hip/hip_runtime.h>
#include <hip/hip_bf16.h>
#include <math.h>

#define B_ 8
#define T_ 2048
#define C_ 1024
#define H_ 64
#define M_ (B_*T_)   // 16384 rows

typedef __attribute__((ext_vector_type(8))) short bf16x8;
typedef __attribute__((ext_vector_type(4))) float floatx4;

// fp32 -> bf16 round-to-nearest-even (cold paths)
static __device__ __forceinline__ unsigned short f2bf(float f) {
    union { float f; unsigned u; } v; v.f = f;
    unsigned r = v.u + 0x7fffu + ((v.u >> 16) & 1u);
    return (unsigned short)(r >> 16);
}
// fp32 -> bf16 round-half-up (2 VALU) for hot paths
static __device__ __forceinline__ unsigned short f2bf_fast(float f) {
    union { float f; unsigned u; } v; v.f = f;
    return (unsigned short)((v.u + 0x8000u) >> 16);
}
// pack two fp32 -> bf16 pair [hi|lo] in 3 VALU (add, add, v_perm)
static __device__ __forceinline__ unsigned pk2h(float lo, float hi) {
    union { float f; unsigned u; } a, b; a.f = lo; b.f = hi;
    return __builtin_amdgcn_perm(b.u + 0x8000u, a.u + 0x8000u, 0x07060302u);
}
static __device__ __forceinline__ bf16x8 cvt8(float4 f0, float4 f1) {
    union { uint4 u; bf16x8 v; } r;
    r.u.x = pk2h(f0.x, f0.y); r.u.y = pk2h(f0.z, f0.w);
    r.u.z = pk2h(f1.x, f1.y); r.u.w = pk2h(f1.z, f1.w);
    return r.v;
}

#define MFMA(a,b,c) __builtin_amdgcn_mfma_f32_16x16x32_bf16((a),(b),(c),0,0,0)

// ---------------------------------------------------------------------------
// Kernel 0: W prep -> wt2 in MFMA B-fragment order.
// wt2 flat index: ((tile*32 + kchunk)*64 + lane)*8, tile=0..11 (16 cols each,
// cols = q|k|v), kchunk=0..31 (32 k each). lane frag: [col=l15][k=quad*8+j].
// q-columns (tile 0..3) pre-scaled by 0.125.
// ---------------------------------------------------------------------------
__global__ __launch_bounds__(256) void wprep_kernel(
    const float* __restrict__ Wq, const float* __restrict__ Wk,
    const float* __restrict__ Wv, unsigned short* __restrict__ wt2)
{
    const int f    = blockIdx.x * 256 + threadIdx.x;  // 0..24575
    const int nt   = f >> 11;
    const int kc   = (f >> 6) & 31;
    const int lane = f & 63;
    const int l15  = lane & 15, quad = lane >> 4;
    const int col  = nt * 16 + l15;                   // 0..191
    const float* W = (col < 64) ? Wq : ((col < 128) ? Wk : Wv);
    const int   cw = col & 63;
    const float sc = (col < 64) ? 0.125f : 1.0f;
    unsigned short o[8];
    #pragma unroll
    for (int j = 0; j < 8; j++) {
        const int kk = kc * 32 + quad * 8 + j;
        o[j] = f2bf(W[(size_t)kk * 64 + cw] * sc);
    }
    *(uint4*)&wt2[(size_t)f * 8] = *(const uint4*)o;
}

// ---------------------------------------------------------------------------
// Kernel 1: QKV projection, bf16 MFMA, barrier-free FULLY-UNROLLED K-loop.
// Grid 512 x 256 thr (4 waves). Block = 32 rows; wave w = cols 48w..48w+47.
// Full unroll exposes all 224 loads to the scheduler for deep MLP;
// launch_bounds(256,2) gives it a 256-VGPR hoisting budget.
// ---------------------------------------------------------------------------
__global__ __launch_bounds__(256, 2) void qkv_kernel(
    const float* __restrict__ x, const unsigned short* __restrict__ wt2,
    unsigned short* __restrict__ qo, unsigned short* __restrict__ ko,
    unsigned short* __restrict__ vo)
{
    __shared__ __align__(16) unsigned short es[32 * 200];  // 12.8 KB epilogue

    const int t    = threadIdx.x;
    const int w    = t >> 6;
    const int lane = t & 63;
    const int l15  = lane & 15;
    const int quad = lane >> 4;
    const int r0   = blockIdx.x * 32;

    floatx4 acc[2][3];
    #pragma unroll
    for (int m = 0; m < 2; m++)
        #pragma unroll
        for (int n = 0; n < 3; n++) acc[m][n] = (floatx4)(0.0f);

    const float*          xa0 = x   + (size_t)(r0 + l15) * C_ + quad * 8;
    const float*          xa1 = xa0 + 16 * C_;
    const unsigned short* wb0 = wt2 + (size_t)(w * 3 + 0) * 32 * 512 + lane * 8;
    const unsigned short* wb1 = wt2 + (size_t)(w * 3 + 1) * 32 * 512 + lane * 8;
    const unsigned short* wb2 = wt2 + (size_t)(w * 3 + 2) * 32 * 512 + lane * 8;

    #pragma unroll
    for (int kc = 0; kc < 32; kc++) {
        const int k0 = kc * 32;
        const float4 x00 = *(const float4*)(xa0 + k0);
        const float4 x01 = *(const float4*)(xa0 + k0 + 4);
        const float4 x10 = *(const float4*)(xa1 + k0);
        const float4 x11 = *(const float4*)(xa1 + k0 + 4);
        const bf16x8 b0  = *(const bf16x8*)(wb0 + (size_t)kc * 512);
        const bf16x8 b1  = *(const bf16x8*)(wb1 + (size_t)kc * 512);
        const bf16x8 b2  = *(const bf16x8*)(wb2 + (size_t)kc * 512);
        const bf16x8 a0  = cvt8(x00, x01);
        const bf16x8 a1  = cvt8(x10, x11);
        acc[0][0] = MFMA(a0, b0, acc[0][0]);
        acc[1][0] = MFMA(a1, b0, acc[1][0]);
        acc[0][1] = MFMA(a0, b1, acc[0][1]);
        acc[1][1] = MFMA(a1, b1, acc[1][1]);
        acc[0][2] = MFMA(a0, b2, acc[0][2]);
        acc[1][2] = MFMA(a1, b2, acc[1][2]);
    }

    // ---- epilogue: repack through LDS, coalesced writes (scale pre-folded) --
    #pragma unroll
    for (int mt = 0; mt < 2; mt++)
        #pragma unroll
        for (int nt = 0; nt < 3; nt++) {
            const int col = w * 48 + nt * 16 + l15;
            #pragma unroll
            for (int r = 0; r < 4; r++)
                es[(mt * 16 + quad * 4 + r) * 200 + col] = f2bf(acc[mt][nt][r]);
        }
    __syncthreads();

    { // q, k: [row][64] bf16
        const int row = t >> 3, oct = t & 7;
        *(uint4*)&qo[(size_t)(r0 + row) * 64 + oct * 8] =
            *(const uint4*)&es[row * 200 + oct * 8];
        *(uint4*)&ko[(size_t)(r0 + row) * 64 + oct * 8] =
            *(const uint4*)&es[row * 200 + 64 + oct * 8];
    }
    { // v: transposed [b][h][t]
        const int h = t >> 2, ts = (t & 3) * 8;
        const int bb = r0 >> 11, tt = r0 & 2047;
        unsigned short tmp[8];
        #pragma unroll
        for (int j = 0; j < 8; j++) tmp[j] = es[(ts + j) * 200 + 128 + h];
        *(uint4*)&vo[((size_t)bb * 64 + h) * 2048 + tt + ts] = *(uint4*)tmp;
    }
}

// ---------------------------------------------------------------------------
// Kernel 2: causal flash attention with ALiBi, bf16 MFMA.
// 256 thr (4 waves); 16-row q-tile; K-range split 4 ways across waves;
// per-wave private softmax state + pT region, no per-step barriers.
// NEW: next-step K/V fragments prefetched under softmax+PV of current step.
// Grid 1024 = 8 batches x 128 q-tiles, heavy-first.
// ---------------------------------------------------------------------------
__global__ __launch_bounds__(256, 2) void attn_kernel(
    const unsigned short* __restrict__ q,
    const unsigned short* __restrict__ k,
    const unsigned short* __restrict__ vT,
    float* __restrict__ out)
{
    // pT during loop: 4 waves x 16x72 halfs = 9216 B at offset 0.
    // merge after barrier: Omg [4][16][64] f32 = 16384 B at 0,
    //                      mlg [4][2][16]  f32 =   512 B at 16384.
    __shared__ __align__(16) unsigned char smem[16384 + 512];
    unsigned short* pT  = (unsigned short*)smem;
    float*          Omg = (float*)smem;
    float*          mlg = (float*)(smem + 16384);

    const int t    = threadIdx.x;
    const int w    = t >> 6;
    const int lane = t & 63;
    const int l15  = lane & 15;
    const int quad = lane >> 4;
    const int b    = blockIdx.x & 7;
    const int qt   = 127 - (blockIdx.x >> 3);   // heavy tiles first
    const int q0   = qt * 16;
    const size_t kb = (size_t)b * T_ * 64;

    // Q A-fragments (scale folded into Wq)
    const bf16x8 qf0 = *(const bf16x8*)&q[kb + (size_t)(q0 + l15) * 64 + quad * 8];
    const bf16x8 qf1 = *(const bf16x8*)&q[kb + (size_t)(q0 + l15) * 64 + 32 + quad * 8];

    floatx4 O[4];
    #pragma unroll
    for (int i = 0; i < 4; i++) O[i] = (floatx4)(0.0f);
    float mrow[4], lrow[4];
    #pragma unroll
    for (int r = 0; r < 4; r++) { mrow[r] = -INFINITY; lrow[r] = 0.0f; }

    const int nk     = q0 + 16;
    const int nsteps = (nk + 63) >> 6;
    const int ns4    = (nsteps + 3) >> 2;
    const int sBeg   = w * ns4;
    const int sEnd   = min(sBeg + ns4, nsteps);
    const float bs   = 0.088388347648318447f;   // 2^-0.5 * 0.125
    const int   ig0  = q0 + quad * 4;
    unsigned short* pw = pT + w * 16 * 72;

    bf16x8 kf[4][2], vf[4][2];
    #define LOADSTEP(dK, dV, jj0)                                              \
        { _Pragma("unroll")                                                    \
          for (int nt = 0; nt < 4; nt++) {                                     \
              _Pragma("unroll")                                                \
              for (int ks = 0; ks < 2; ks++) {                                 \
                  dK[nt][ks] = *(const bf16x8*)                                \
                      &k[kb + (size_t)((jj0) + nt*16 + l15)*64 + ks*32 + quad*8]; \
                  dV[nt][ks] = *(const bf16x8*)                                \
                      &vT[((size_t)b*64 + nt*16 + l15)*2048 + (jj0) + ks*32 + quad*8]; \
              } } }

    if (sBeg < sEnd) LOADSTEP(kf, vf, sBeg * 64)

    #pragma unroll 2
    for (int s = sBeg; s < sEnd; s++) {
        const int j0 = s * 64;

        // ---- S = Q K^T over 64 keys (uses current kf) ----
        floatx4 sc[4];
        #pragma unroll
        for (int nt = 0; nt < 4; nt++) {
            floatx4 z = (floatx4)(0.0f);
            z = MFMA(qf0, kf[nt][0], z);
            z = MFMA(qf1, kf[nt][1], z);
            sc[nt] = z;
        }

        // ---- prefetch next step's K/V under softmax+PV ----
        bf16x8 kf2[4][2], vf2[4][2];
        const bool more = (s + 1 < sEnd);
        if (more) LOADSTEP(kf2, vf2, (s + 1) * 64)

        // ---- ALiBi + causal + online softmax (deferred l-reduce) ----
        #pragma unroll
        for (int r = 0; r < 4; r++) {
            const int ig = ig0 + r;
            float xv[4];
            float mloc = -INFINITY;
            #pragma unroll
            for (int nt = 0; nt < 4; nt++) {
                const int j = j0 + nt * 16 + l15;
                float v2 = sc[nt][r] + (float)(j - ig) * bs;
                if (j > ig) v2 = -INFINITY;
                xv[nt] = v2;
                mloc = fmaxf(mloc, v2);
            }
            #pragma unroll
            for (int off = 1; off < 16; off <<= 1)
                mloc = fmaxf(mloc, __shfl_xor(mloc, off));
            const float mnew = fmaxf(mrow[r], mloc);
            const float mq   = (mnew == -INFINITY) ? 0.0f : mnew;
            const float alpha = __expf(mrow[r] - mq);
            mrow[r] = mnew;
            float ps = 0.0f;
            #pragma unroll
            for (int nt = 0; nt < 4; nt++) {
                const float p = __expf(xv[nt] - mq);
                ps += p;
                pw[(quad * 4 + r) * 72 + nt * 16 + l15] = f2bf_fast(p);
            }
            lrow[r] = lrow[r] * alpha + ps;     // per-lane partial; reduced at end
            #pragma unroll
            for (int nt = 0; nt < 4; nt++) O[nt][r] *= alpha;
        }

        // ---- O += P V  (same-wave DS in-order; no barrier) ----
        const bf16x8 pf0 = *(const bf16x8*)&pw[l15 * 72 + quad * 8];
        const bf16x8 pf1 = *(const bf16x8*)&pw[l15 * 72 + 32 + quad * 8];
        #pragma unroll
        for (int nt = 0; nt < 4; nt++) {
            O[nt] = MFMA(pf0, vf[nt][0], O[nt]);
            O[nt] = MFMA(pf1, vf[nt][1], O[nt]);
        }

        if (more) {
            #pragma unroll
            for (int nt = 0; nt < 4; nt++)
                #pragma unroll
                for (int ks = 0; ks < 2; ks++) {
                    kf[nt][ks] = kf2[nt][ks];
                    vf[nt][ks] = vf2[nt][ks];
                }
        }
    }
    #undef LOADSTEP

    // ---- reduce per-lane l partials across the 16 key-lanes ----
    #pragma unroll
    for (int r = 0; r < 4; r++)
        #pragma unroll
        for (int off = 1; off < 16; off <<= 1)
            lrow[r] += __shfl_xor(lrow[r], off);

    __syncthreads();   // all waves done with pT

    // ---- publish partial state ----
    #pragma unroll
    for (int nt = 0; nt < 4; nt++)
        #pragma unroll
        for (int r = 0; r < 4; r++)
            Omg[w * 1024 + (quad * 4 + r) * 64 + nt * 16 + l15] = O[nt][r];
    if (l15 == 0) {
        #pragma unroll
        for (int r = 0; r < 4; r++) {
            mlg[w * 32 + (quad * 4 + r)]      = mrow[r];
            mlg[w * 32 + 16 + (quad * 4 + r)] = lrow[r];
        }
    }
    __syncthreads();

    // ---- merge 4 partials, write output ----
    {
        const int row = t >> 4;          // 0..15
        const int hq  = (t & 15) << 2;   // 0..60
        float mstar = -INFINITY;
        #pragma unroll
        for (int w2 = 0; w2 < 4; w2++)
            mstar = fmaxf(mstar, mlg[w2 * 32 + row]);
        floatx4 oa = (floatx4)(0.0f);
        float lsum = 0.0f;
        #pragma unroll
        for (int w2 = 0; w2 < 4; w2++) {
            const float wg = __expf(mlg[w2 * 32 + row] - mstar);
            lsum += wg * mlg[w2 * 32 + 16 + row];
            const floatx4 ov = *(const floatx4*)&Omg[w2 * 1024 + row * 64 + hq];
            oa += wg * ov;
        }
        const float inv = 1.0f / lsum;
        *(floatx4*)&out[kb + (size_t)(q0 + row) * 64 + hq] = oa * inv;
    }
}

extern "C" void kernel_launch(void* const* d_in, const int* in_sizes, int n_in,
                              void* d_out, int out_size, void* d_ws, size_t ws_size,
                              hipStream_t stream) {
    (void)in_sizes; (void)n_in; (void)out_size; (void)ws_size;
    const float* x  = (const float*)d_in[0];
    const float* Wq = (const float*)d_in[1];
    const float* Wk = (const float*)d_in[2];
    const float* Wv = (const float*)d_in[3];
    float* out = (float*)d_out;

    unsigned short* wt2 = (unsigned short*)d_ws;                // [12][32][64][8]
    unsigned short* qw  = wt2 + 196608;                         // [M][64]
    unsigned short* kw  = qw + (size_t)M_ * H_;                 // [M][64]
    unsigned short* vw  = kw + (size_t)M_ * H_;                 // [B][64][2048]

    wprep_kernel<<<96, 256, 0, stream>>>(Wq, Wk, Wv, wt2);
    qkv_kernel<<<M_ / 32, 256, 0, stream>>>(x, wt2, qw, kw, vw);
    attn_kernel<<<B_ * 128, 256, 0, stream>>>(qw, kw, vw, out);
}

// Round 6
// 169.783 us; speedup vs baseline: 1.0186x; 1.0186x over previous
//
#include <hip/hip_runtime.h>
#include <hip/hip_bf16.h>
#include <math.h>

#define B_ 8
#define T_ 2048
#define C_ 1024
#define H_ 64
#define M_ (B_*T_)   // 16384 rows

typedef __attribute__((ext_vector_type(8))) short bf16x8;
typedef __attribute__((ext_vector_type(4))) float floatx4;

// fp32 -> bf16 round-to-nearest-even (cold paths)
static __device__ __forceinline__ unsigned short f2bf(float f) {
    union { float f; unsigned u; } v; v.f = f;
    unsigned r = v.u + 0x7fffu + ((v.u >> 16) & 1u);
    return (unsigned short)(r >> 16);
}
// fp32 -> bf16 round-half-up (2 VALU) for hot paths
static __device__ __forceinline__ unsigned short f2bf_fast(float f) {
    union { float f; unsigned u; } v; v.f = f;
    return (unsigned short)((v.u + 0x8000u) >> 16);
}
// pack two fp32 -> bf16 pair [hi|lo] in 3 VALU (add, add, v_perm)
static __device__ __forceinline__ unsigned pk2h(float lo, float hi) {
    union { float f; unsigned u; } a, b; a.f = lo; b.f = hi;
    return __builtin_amdgcn_perm(b.u + 0x8000u, a.u + 0x8000u, 0x07060302u);
}
static __device__ __forceinline__ bf16x8 cvt8(float4 f0, float4 f1) {
    union { uint4 u; bf16x8 v; } r;
    r.u.x = pk2h(f0.x, f0.y); r.u.y = pk2h(f0.z, f0.w);
    r.u.z = pk2h(f1.x, f1.y); r.u.w = pk2h(f1.z, f1.w);
    return r.v;
}

#define MFMA(a,b,c) __builtin_amdgcn_mfma_f32_16x16x32_bf16((a),(b),(c),0,0,0)

// ---------------------------------------------------------------------------
// Kernel 0: W prep -> wt2 in MFMA B-fragment order.
// wt2 flat index: ((tile*32 + kchunk)*64 + lane)*8, tile=0..11 (16 cols each,
// cols = q|k|v), kchunk=0..31 (32 k each). lane frag: [col=l15][k=quad*8+j].
// q-columns (tile 0..3) pre-scaled by 0.125.
// ---------------------------------------------------------------------------
__global__ __launch_bounds__(256) void wprep_kernel(
    const float* __restrict__ Wq, const float* __restrict__ Wk,
    const float* __restrict__ Wv, unsigned short* __restrict__ wt2)
{
    const int f    = blockIdx.x * 256 + threadIdx.x;  // 0..24575
    const int nt   = f >> 11;
    const int kc   = (f >> 6) & 31;
    const int lane = f & 63;
    const int l15  = lane & 15, quad = lane >> 4;
    const int col  = nt * 16 + l15;                   // 0..191
    const float* W = (col < 64) ? Wq : ((col < 128) ? Wk : Wv);
    const int   cw = col & 63;
    const float sc = (col < 64) ? 0.125f : 1.0f;
    unsigned short o[8];
    #pragma unroll
    for (int j = 0; j < 8; j++) {
        const int kk = kc * 32 + quad * 8 + j;
        o[j] = f2bf(W[(size_t)kk * 64 + cw] * sc);
    }
    *(uint4*)&wt2[(size_t)f * 8] = *(const uint4*)o;
}

// ---------------------------------------------------------------------------
// Kernel 1: QKV projection, bf16 MFMA, barrier-free K-loop.
// Grid 1024 x 256 thr (4 waves) -> 4096 waves = 4 waves/SIMD for latency
// hiding. Block = 16 rows x 192 cols; wave w = cols 48w..48w+47 (3 tiles).
// 64-k chunks: 2 A-frags (direct from x, fp32->bf16 in regs) x 3 B-frag
// pairs (coalesced 1KB wave loads from fragment-ordered, L2-resident wt2).
// ---------------------------------------------------------------------------
__global__ __launch_bounds__(256) void qkv_kernel(
    const float* __restrict__ x, const unsigned short* __restrict__ wt2,
    unsigned short* __restrict__ qo, unsigned short* __restrict__ ko,
    unsigned short* __restrict__ vo)
{
    __shared__ __align__(16) unsigned short es[16 * 200];  // 6.4 KB epilogue

    const int t    = threadIdx.x;
    const int w    = t >> 6;
    const int lane = t & 63;
    const int l15  = lane & 15;
    const int quad = lane >> 4;
    const int r0   = blockIdx.x * 16;

    floatx4 acc0 = (floatx4)(0.0f), acc1 = (floatx4)(0.0f), acc2 = (floatx4)(0.0f);

    const float*          xa = x   + (size_t)(r0 + l15) * C_ + quad * 8;
    const unsigned short* wb = wt2 + (size_t)(w * 3) * 32 * 512 + lane * 8;

    #pragma unroll 2
    for (int kc = 0; kc < 16; kc++) {
        const int k0 = kc * 64;
        const float4 x00 = *(const float4*)(xa + k0);
        const float4 x01 = *(const float4*)(xa + k0 + 4);
        const float4 x10 = *(const float4*)(xa + k0 + 32);
        const float4 x11 = *(const float4*)(xa + k0 + 36);
        const bf16x8 b0l = *(const bf16x8*)(wb + (size_t)(0 * 32 + 2 * kc) * 512);
        const bf16x8 b0h = *(const bf16x8*)(wb + (size_t)(0 * 32 + 2 * kc + 1) * 512);
        const bf16x8 b1l = *(const bf16x8*)(wb + (size_t)(1 * 32 + 2 * kc) * 512);
        const bf16x8 b1h = *(const bf16x8*)(wb + (size_t)(1 * 32 + 2 * kc + 1) * 512);
        const bf16x8 b2l = *(const bf16x8*)(wb + (size_t)(2 * 32 + 2 * kc) * 512);
        const bf16x8 b2h = *(const bf16x8*)(wb + (size_t)(2 * 32 + 2 * kc + 1) * 512);
        const bf16x8 a0  = cvt8(x00, x01);
        const bf16x8 a1  = cvt8(x10, x11);
        acc0 = MFMA(a0, b0l, acc0);  acc0 = MFMA(a1, b0h, acc0);
        acc1 = MFMA(a0, b1l, acc1);  acc1 = MFMA(a1, b1h, acc1);
        acc2 = MFMA(a0, b2l, acc2);  acc2 = MFMA(a1, b2h, acc2);
    }

    // ---- epilogue: repack through LDS, coalesced writes (scale pre-folded) --
    {
        const floatx4 av[3] = {acc0, acc1, acc2};
        #pragma unroll
        for (int nt = 0; nt < 3; nt++) {
            const int col = w * 48 + nt * 16 + l15;
            #pragma unroll
            for (int r = 0; r < 4; r++)
                es[(quad * 4 + r) * 200 + col] = f2bf(av[nt][r]);
        }
    }
    __syncthreads();

    { // q, k: [row][64] bf16 — 2 halves x 16 rows x 8 octs = 256 threads
        const int m   = t >> 7;
        const int row = (t >> 3) & 15;
        const int oct = t & 7;
        unsigned short* outp = m ? ko : qo;
        *(uint4*)&outp[(size_t)(r0 + row) * 64 + oct * 8] =
            *(const uint4*)&es[row * 200 + m * 64 + oct * 8];
    }
    { // v: transposed [b][h][t] — 64 h x 4 t-groups = 256 threads
        const int h  = t >> 2;
        const int j0 = (t & 3) * 4;
        const int bb = r0 >> 11, tt = r0 & 2047;
        __align__(8) unsigned short tmp[4];
        #pragma unroll
        for (int j = 0; j < 4; j++) tmp[j] = es[(j0 + j) * 200 + 128 + h];
        *(uint2*)&vo[((size_t)bb * 64 + h) * 2048 + tt + j0] = *(uint2*)tmp;
    }
}

// ---------------------------------------------------------------------------
// Kernel 2: causal flash attention with ALiBi, bf16 MFMA.
// 256 thr (4 waves); 16-row q-tile; K-range split 4 ways across waves;
// per-wave private softmax state + pT region, no per-step barriers;
// next-step K/V fragments prefetched under softmax+PV of current step.
// Grid 1024 = 8 batches x 128 q-tiles, heavy-first.
// ---------------------------------------------------------------------------
__global__ __launch_bounds__(256, 2) void attn_kernel(
    const unsigned short* __restrict__ q,
    const unsigned short* __restrict__ k,
    const unsigned short* __restrict__ vT,
    float* __restrict__ out)
{
    // pT during loop: 4 waves x 16x72 halfs = 9216 B at offset 0.
    // merge after barrier: Omg [4][16][64] f32 = 16384 B at 0,
    //                      mlg [4][2][16]  f32 =   512 B at 16384.
    __shared__ __align__(16) unsigned char smem[16384 + 512];
    unsigned short* pT  = (unsigned short*)smem;
    float*          Omg = (float*)smem;
    float*          mlg = (float*)(smem + 16384);

    const int t    = threadIdx.x;
    const int w    = t >> 6;
    const int lane = t & 63;
    const int l15  = lane & 15;
    const int quad = lane >> 4;
    const int b    = blockIdx.x & 7;
    const int qt   = 127 - (blockIdx.x >> 3);   // heavy tiles first
    const int q0   = qt * 16;
    const size_t kb = (size_t)b * T_ * 64;

    // Q A-fragments (scale folded into Wq)
    const bf16x8 qf0 = *(const bf16x8*)&q[kb + (size_t)(q0 + l15) * 64 + quad * 8];
    const bf16x8 qf1 = *(const bf16x8*)&q[kb + (size_t)(q0 + l15) * 64 + 32 + quad * 8];

    floatx4 O[4];
    #pragma unroll
    for (int i = 0; i < 4; i++) O[i] = (floatx4)(0.0f);
    float mrow[4], lrow[4];
    #pragma unroll
    for (int r = 0; r < 4; r++) { mrow[r] = -INFINITY; lrow[r] = 0.0f; }

    const int nk     = q0 + 16;
    const int nsteps = (nk + 63) >> 6;
    const int ns4    = (nsteps + 3) >> 2;
    const int sBeg   = w * ns4;
    const int sEnd   = min(sBeg + ns4, nsteps);
    const float bs   = 0.088388347648318447f;   // 2^-0.5 * 0.125
    const int   ig0  = q0 + quad * 4;
    unsigned short* pw = pT + w * 16 * 72;

    bf16x8 kf[4][2], vf[4][2];
    #define LOADSTEP(dK, dV, jj0)                                              \
        { _Pragma("unroll")                                                    \
          for (int nt = 0; nt < 4; nt++) {                                     \
              _Pragma("unroll")                                                \
              for (int ks = 0; ks < 2; ks++) {                                 \
                  dK[nt][ks] = *(const bf16x8*)                                \
                      &k[kb + (size_t)((jj0) + nt*16 + l15)*64 + ks*32 + quad*8]; \
                  dV[nt][ks] = *(const bf16x8*)                                \
                      &vT[((size_t)b*64 + nt*16 + l15)*2048 + (jj0) + ks*32 + quad*8]; \
              } } }

    if (sBeg < sEnd) LOADSTEP(kf, vf, sBeg * 64)

    #pragma unroll 2
    for (int s = sBeg; s < sEnd; s++) {
        const int j0 = s * 64;

        // ---- S = Q K^T over 64 keys (uses current kf) ----
        floatx4 sc[4];
        #pragma unroll
        for (int nt = 0; nt < 4; nt++) {
            floatx4 z = (floatx4)(0.0f);
            z = MFMA(qf0, kf[nt][0], z);
            z = MFMA(qf1, kf[nt][1], z);
            sc[nt] = z;
        }

        // ---- prefetch next step's K/V under softmax+PV ----
        bf16x8 kf2[4][2], vf2[4][2];
        const bool more = (s + 1 < sEnd);
        if (more) LOADSTEP(kf2, vf2, (s + 1) * 64)

        // ---- ALiBi + causal + online softmax (deferred l-reduce) ----
        #pragma unroll
        for (int r = 0; r < 4; r++) {
            const int ig = ig0 + r;
            float xv[4];
            float mloc = -INFINITY;
            #pragma unroll
            for (int nt = 0; nt < 4; nt++) {
                const int j = j0 + nt * 16 + l15;
                float v2 = sc[nt][r] + (float)(j - ig) * bs;
                if (j > ig) v2 = -INFINITY;
                xv[nt] = v2;
                mloc = fmaxf(mloc, v2);
            }
            #pragma unroll
            for (int off = 1; off < 16; off <<= 1)
                mloc = fmaxf(mloc, __shfl_xor(mloc, off));
            const float mnew = fmaxf(mrow[r], mloc);
            const float mq   = (mnew == -INFINITY) ? 0.0f : mnew;
            const float alpha = __expf(mrow[r] - mq);
            mrow[r] = mnew;
            float ps = 0.0f;
            #pragma unroll
            for (int nt = 0; nt < 4; nt++) {
                const float p = __expf(xv[nt] - mq);
                ps += p;
                pw[(quad * 4 + r) * 72 + nt * 16 + l15] = f2bf_fast(p);
            }
            lrow[r] = lrow[r] * alpha + ps;     // per-lane partial; reduced at end
            #pragma unroll
            for (int nt = 0; nt < 4; nt++) O[nt][r] *= alpha;
        }

        // ---- O += P V  (same-wave DS in-order; no barrier) ----
        const bf16x8 pf0 = *(const bf16x8*)&pw[l15 * 72 + quad * 8];
        const bf16x8 pf1 = *(const bf16x8*)&pw[l15 * 72 + 32 + quad * 8];
        #pragma unroll
        for (int nt = 0; nt < 4; nt++) {
            O[nt] = MFMA(pf0, vf[nt][0], O[nt]);
            O[nt] = MFMA(pf1, vf[nt][1], O[nt]);
        }

        if (more) {
            #pragma unroll
            for (int nt = 0; nt < 4; nt++)
                #pragma unroll
                for (int ks = 0; ks < 2; ks++) {
                    kf[nt][ks] = kf2[nt][ks];
                    vf[nt][ks] = vf2[nt][ks];
                }
        }
    }
    #undef LOADSTEP

    // ---- reduce per-lane l partials across the 16 key-lanes ----
    #pragma unroll
    for (int r = 0; r < 4; r++)
        #pragma unroll
        for (int off = 1; off < 16; off <<= 1)
            lrow[r] += __shfl_xor(lrow[r], off);

    __syncthreads();   // all waves done with pT

    // ---- publish partial state ----
    #pragma unroll
    for (int nt = 0; nt < 4; nt++)
        #pragma unroll
        for (int r = 0; r < 4; r++)
            Omg[w * 1024 + (quad * 4 + r) * 64 + nt * 16 + l15] = O[nt][r];
    if (l15 == 0) {
        #pragma unroll
        for (int r = 0; r < 4; r++) {
            mlg[w * 32 + (quad * 4 + r)]      = mrow[r];
            mlg[w * 32 + 16 + (quad * 4 + r)] = lrow[r];
        }
    }
    __syncthreads();

    // ---- merge 4 partials, write output ----
    {
        const int row = t >> 4;          // 0..15
        const int hq  = (t & 15) << 2;   // 0..60
        float mstar = -INFINITY;
        #pragma unroll
        for (int w2 = 0; w2 < 4; w2++)
            mstar = fmaxf(mstar, mlg[w2 * 32 + row]);
        floatx4 oa = (floatx4)(0.0f);
        float lsum = 0.0f;
        #pragma unroll
        for (int w2 = 0; w2 < 4; w2++) {
            const float wg = __expf(mlg[w2 * 32 + row] - mstar);
            lsum += wg * mlg[w2 * 32 + 16 + row];
            const floatx4 ov = *(const floatx4*)&Omg[w2 * 1024 + row * 64 + hq];
            oa += wg * ov;
        }
        const float inv = 1.0f / lsum;
        *(floatx4*)&out[kb + (size_t)(q0 + row) * 64 + hq] = oa * inv;
    }
}

extern "C" void kernel_launch(void* const* d_in, const int* in_sizes, int n_in,
                              void* d_out, int out_size, void* d_ws, size_t ws_size,
                              hipStream_t stream) {
    (void)in_sizes; (void)n_in; (void)out_size; (void)ws_size;
    const float* x  = (const float*)d_in[0];
    const float* Wq = (const float*)d_in[1];
    const float* Wk = (const float*)d_in[2];
    const float* Wv = (const float*)d_in[3];
    float* out = (float*)d_out;

    unsigned short* wt2 = (unsigned short*)d_ws;                // [12][32][64][8]
    unsigned short* qw  = wt2 + 196608;                         // [M][64]
    unsigned short* kw  = qw + (size_t)M_ * H_;                 // [M][64]
    unsigned short* vw  = kw + (size_t)M_ * H_;                 // [B][64][2048]

    wprep_kernel<<<96, 256, 0, stream>>>(Wq, Wk, Wv, wt2);
    qkv_kernel<<<M_ / 16, 256, 0, stream>>>(x, wt2, qw, kw, vw);
    attn_kernel<<<B_ * 128, 256, 0, stream>>>(qw, kw, vw, out);
}

// Round 7
// 144.748 us; speedup vs baseline: 1.1948x; 1.1730x over previous
//
#include <hip/hip_runtime.h>
#include <hip/hip_bf16.h>
#include <math.h>

#define B_ 8
#define T_ 2048
#define C_ 1024
#define H_ 64
#define M_ (B_*T_)   // 16384 rows

typedef __attribute__((ext_vector_type(8))) short bf16x8;
typedef __attribute__((ext_vector_type(4))) float floatx4;

// fp32 -> bf16 round-to-nearest-even (cold paths)
static __device__ __forceinline__ unsigned short f2bf(float f) {
    union { float f; unsigned u; } v; v.f = f;
    unsigned r = v.u + 0x7fffu + ((v.u >> 16) & 1u);
    return (unsigned short)(r >> 16);
}
// fp32 -> bf16 round-half-up (2 VALU) for hot paths
static __device__ __forceinline__ unsigned short f2bf_fast(float f) {
    union { float f; unsigned u; } v; v.f = f;
    return (unsigned short)((v.u + 0x8000u) >> 16);
}
// pack two fp32 -> bf16 pair [hi|lo] in 3 VALU (add, add, v_perm)
static __device__ __forceinline__ unsigned pk2h(float lo, float hi) {
    union { float f; unsigned u; } a, b; a.f = lo; b.f = hi;
    return __builtin_amdgcn_perm(b.u + 0x8000u, a.u + 0x8000u, 0x07060302u);
}
static __device__ __forceinline__ bf16x8 cvt8(float4 f0, float4 f1) {
    union { uint4 u; bf16x8 v; } r;
    r.u.x = pk2h(f0.x, f0.y); r.u.y = pk2h(f0.z, f0.w);
    r.u.z = pk2h(f1.x, f1.y); r.u.w = pk2h(f1.z, f1.w);
    return r.v;
}

#define MFMA(a,b,c) __builtin_amdgcn_mfma_f32_16x16x32_bf16((a),(b),(c),0,0,0)

// ---------------------------------------------------------------------------
// Kernel 0: W prep -> wt2 in MFMA B-fragment order.
// wt2 flat: ((tile*32 + kchunk)*64 + lane)*8; tile=0..11 (16 cols, q|k|v),
// kchunk=0..31 (32 k each); lane frag [col=l15][k=quad*8+j].
// q-columns (tiles 0..3) pre-scaled by 0.125.
// ---------------------------------------------------------------------------
__global__ __launch_bounds__(256) void wprep_kernel(
    const float* __restrict__ Wq, const float* __restrict__ Wk,
    const float* __restrict__ Wv, unsigned short* __restrict__ wt2)
{
    const int f    = blockIdx.x * 256 + threadIdx.x;  // 0..24575
    const int nt   = f >> 11;
    const int kc   = (f >> 6) & 31;
    const int lane = f & 63;
    const int l15  = lane & 15, quad = lane >> 4;
    const int col  = nt * 16 + l15;                   // 0..191
    const float* W = (col < 64) ? Wq : ((col < 128) ? Wk : Wv);
    const int   cw = col & 63;
    const float sc = (col < 64) ? 0.125f : 1.0f;
    unsigned short o[8];
    #pragma unroll
    for (int j = 0; j < 8; j++) {
        const int kk = kc * 32 + quad * 8 + j;
        o[j] = f2bf(W[(size_t)kk * 64 + cw] * sc);
    }
    *(uint4*)&wt2[(size_t)f * 8] = *(const uint4*)o;
}

// ---------------------------------------------------------------------------
// Kernel 1: QKV projection. Grid 256 x 256 thr. Block = 64 rows x 192 cols.
// x staged cooperatively ONCE per block (fp32->bf16 in regs) into a
// double-buffered LDS tile [64][72] bf16; W split by wave (48 cols each),
// fragment-ordered direct loads. x & W prefetched one 64-k chunk ahead.
// Per-CU line traffic: x 4K + W 6K lines (vs 40K in R6).
// ---------------------------------------------------------------------------
__global__ __launch_bounds__(256) void qkv_kernel(
    const float* __restrict__ x, const unsigned short* __restrict__ wt2,
    unsigned short* __restrict__ qo, unsigned short* __restrict__ ko,
    unsigned short* __restrict__ vo)
{
    // union: xs[2][64*72] (18.4 KB) during loop; es[64][200] (25.6 KB) epilogue
    __shared__ __align__(16) unsigned short smem[64 * 200];
    #define XS_(buf) (smem + (buf) * 4608)

    const int t    = threadIdx.x;
    const int w    = t >> 6;
    const int lane = t & 63;
    const int l15  = lane & 15;
    const int quad = lane >> 4;
    const int r0   = blockIdx.x * 64;

    // staging map: row = t>>2 (0..63), g in {t&3, (t&3)+4} (8 floats each)
    const int srow = t >> 2;
    const int g0   = t & 3;
    const float* xrow = x + (size_t)(r0 + srow) * C_;

    // W pointers: wave w owns tiles w*3 .. w*3+2
    const unsigned short* wb = wt2 + (size_t)(w * 3) * 32 * 512 + lane * 8;

    floatx4 acc[4][3];
    #pragma unroll
    for (int mt = 0; mt < 4; mt++)
        #pragma unroll
        for (int nt = 0; nt < 3; nt++) acc[mt][nt] = (floatx4)(0.0f);

    // ---- stage chunk 0 + load W chunk 0 ----
    bf16x8 wcur[6];
    {
        #pragma unroll
        for (int j = 0; j < 2; j++) {
            const int g = g0 + 4 * j;
            const float4 f0 = *(const float4*)(xrow + g * 8);
            const float4 f1 = *(const float4*)(xrow + g * 8 + 4);
            *(bf16x8*)(XS_(0) + srow * 72 + g * 8) = cvt8(f0, f1);
        }
        #pragma unroll
        for (int nt = 0; nt < 3; nt++)
            #pragma unroll
            for (int ks = 0; ks < 2; ks++)
                wcur[nt * 2 + ks] = *(const bf16x8*)(wb + (size_t)(nt * 32 + ks) * 512);
    }
    __syncthreads();

    for (int c = 0; c < 16; c++) {
        const int buf = c & 1;

        // ---- prefetch chunk c+1 (x -> regs, W -> regs) ----
        float4 xn[4];
        bf16x8 wn[6];
        if (c < 15) {
            const int k1 = (c + 1) * 64;
            #pragma unroll
            for (int j = 0; j < 2; j++) {
                const int g = g0 + 4 * j;
                xn[j * 2 + 0] = *(const float4*)(xrow + k1 + g * 8);
                xn[j * 2 + 1] = *(const float4*)(xrow + k1 + g * 8 + 4);
            }
            #pragma unroll
            for (int nt = 0; nt < 3; nt++)
                #pragma unroll
                for (int ks = 0; ks < 2; ks++)
                    wn[nt * 2 + ks] = *(const bf16x8*)
                        (wb + (size_t)(nt * 32 + 2 * (c + 1) + ks) * 512);
        }

        // ---- compute chunk c: 24 MFMA ----
        #pragma unroll
        for (int ks = 0; ks < 2; ks++) {
            bf16x8 af[4];
            #pragma unroll
            for (int mt = 0; mt < 4; mt++)
                af[mt] = *(const bf16x8*)
                    (XS_(buf) + (mt * 16 + l15) * 72 + ks * 32 + quad * 8);
            #pragma unroll
            for (int mt = 0; mt < 4; mt++)
                #pragma unroll
                for (int nt = 0; nt < 3; nt++)
                    acc[mt][nt] = MFMA(af[mt], wcur[nt * 2 + ks], acc[mt][nt]);
        }

        // ---- stage chunk c+1 into other buffer ----
        if (c < 15) {
            #pragma unroll
            for (int j = 0; j < 2; j++) {
                const int g = g0 + 4 * j;
                *(bf16x8*)(XS_(buf ^ 1) + srow * 72 + g * 8) =
                    cvt8(xn[j * 2 + 0], xn[j * 2 + 1]);
            }
            #pragma unroll
            for (int i = 0; i < 6; i++) wcur[i] = wn[i];
        }
        __syncthreads();
    }

    // ---- epilogue: repack through LDS (es aliases xs; loop-end barrier done) --
    #pragma unroll
    for (int mt = 0; mt < 4; mt++)
        #pragma unroll
        for (int nt = 0; nt < 3; nt++) {
            const int col = w * 48 + nt * 16 + l15;
            #pragma unroll
            for (int r = 0; r < 4; r++)
                smem[(mt * 16 + quad * 4 + r) * 200 + col] = f2bf(acc[mt][nt][r]);
        }
    __syncthreads();

    { // q, k: [row][64] bf16
        #pragma unroll
        for (int i = 0; i < 2; i++) {
            const int fo  = t + i * 256;      // 0..511
            const int row = fo >> 3;
            const int oct = fo & 7;
            *(uint4*)&qo[(size_t)(r0 + row) * 64 + oct * 8] =
                *(const uint4*)&smem[row * 200 + oct * 8];
            *(uint4*)&ko[(size_t)(r0 + row) * 64 + oct * 8] =
                *(const uint4*)&smem[row * 200 + 64 + oct * 8];
        }
    }
    { // v: transposed [b][h][t]
        const int h = t >> 2, ts = (t & 3) * 16;
        const int bb = r0 >> 11, tt = r0 & 2047;
        unsigned short tmp[16];
        #pragma unroll
        for (int j = 0; j < 16; j++) tmp[j] = smem[(ts + j) * 200 + 128 + h];
        #pragma unroll
        for (int j = 0; j < 2; j++)
            *(uint4*)&vo[((size_t)bb * 64 + h) * 2048 + tt + ts + j * 8] =
                *(uint4*)&tmp[j * 8];
    }
    #undef XS_
}

// ---------------------------------------------------------------------------
// Kernel 2: causal flash attention with ALiBi, bf16 MFMA.
// 256 thr (4 waves); 32-row q-tile (2 row-tiles per wave -> K/V fragments
// reused 2x); K-range split 4 ways across waves; per-wave private softmax
// state + pT region, no per-step barriers; next-step K/V prefetched.
// Grid 512 = 8 batches x 64 q-tiles, heavy-first.
// ---------------------------------------------------------------------------
__global__ __launch_bounds__(256, 2) void attn_kernel(
    const unsigned short* __restrict__ q,
    const unsigned short* __restrict__ k,
    const unsigned short* __restrict__ vT,
    float* __restrict__ out)
{
    // pT during loop: 4 waves x 32x72 halfs = 18432 B at offset 0.
    // merge after barrier: Omg [4][32][64] f32 = 32768 B at 0,
    //                      mlg [4][2][32]  f32 =  1024 B at 32768.
    __shared__ __align__(16) unsigned char smem[32768 + 1024];
    unsigned short* pT  = (unsigned short*)smem;
    float*          Omg = (float*)smem;
    float*          mlg = (float*)(smem + 32768);

    const int t    = threadIdx.x;
    const int w    = t >> 6;
    const int lane = t & 63;
    const int l15  = lane & 15;
    const int quad = lane >> 4;
    const int b    = blockIdx.x & 7;
    const int qt   = 63 - (blockIdx.x >> 3);   // heavy tiles first
    const int q0   = qt * 32;
    const size_t kb = (size_t)b * T_ * 64;

    // Q A-fragments for both row-tiles (scale folded into Wq)
    bf16x8 qf[2][2];
    #pragma unroll
    for (int rt = 0; rt < 2; rt++)
        #pragma unroll
        for (int ks = 0; ks < 2; ks++)
            qf[rt][ks] = *(const bf16x8*)
                &q[kb + (size_t)(q0 + rt * 16 + l15) * 64 + ks * 32 + quad * 8];

    floatx4 O[2][4];
    float mrow[2][4], lrow[2][4];
    #pragma unroll
    for (int rt = 0; rt < 2; rt++) {
        #pragma unroll
        for (int nt = 0; nt < 4; nt++) O[rt][nt] = (floatx4)(0.0f);
        #pragma unroll
        for (int r = 0; r < 4; r++) { mrow[rt][r] = -INFINITY; lrow[rt][r] = 0.0f; }
    }

    const int nsteps = (q0 + 32 + 63) >> 6;
    const int ns4    = (nsteps + 3) >> 2;
    const int sBeg   = w * ns4;
    const int sEnd   = min(sBeg + ns4, nsteps);
    const float bs   = 0.088388347648318447f;   // 2^-0.5 * 0.125
    unsigned short* pw = pT + w * 32 * 72;

    bf16x8 kf[4][2], vf[4][2];
    #define LOADSTEP(dK, dV, jj0)                                              \
        { _Pragma("unroll")                                                    \
          for (int nt = 0; nt < 4; nt++) {                                     \
              _Pragma("unroll")                                                \
              for (int ks = 0; ks < 2; ks++) {                                 \
                  dK[nt][ks] = *(const bf16x8*)                                \
                      &k[kb + (size_t)((jj0) + nt*16 + l15)*64 + ks*32 + quad*8]; \
                  dV[nt][ks] = *(const bf16x8*)                                \
                      &vT[((size_t)b*64 + nt*16 + l15)*2048 + (jj0) + ks*32 + quad*8]; \
              } } }

    if (sBeg < sEnd) LOADSTEP(kf, vf, sBeg * 64)

    for (int s = sBeg; s < sEnd; s++) {
        const int j0 = s * 64;

        // ---- S = Q K^T for both row-tiles ----
        floatx4 sc[2][4];
        #pragma unroll
        for (int rt = 0; rt < 2; rt++)
            #pragma unroll
            for (int nt = 0; nt < 4; nt++) {
                floatx4 z = (floatx4)(0.0f);
                z = MFMA(qf[rt][0], kf[nt][0], z);
                z = MFMA(qf[rt][1], kf[nt][1], z);
                sc[rt][nt] = z;
            }

        // ---- prefetch next step's K/V under softmax+PV ----
        bf16x8 kf2[4][2], vf2[4][2];
        const bool more = (s + 1 < sEnd);
        if (more) LOADSTEP(kf2, vf2, (s + 1) * 64)

        // ---- ALiBi + causal + online softmax (deferred l-reduce) ----
        #pragma unroll
        for (int rt = 0; rt < 2; rt++)
            #pragma unroll
            for (int r = 0; r < 4; r++) {
                const int ig = q0 + rt * 16 + quad * 4 + r;
                float xv[4];
                float mloc = -INFINITY;
                #pragma unroll
                for (int nt = 0; nt < 4; nt++) {
                    const int j = j0 + nt * 16 + l15;
                    float v2 = sc[rt][nt][r] + (float)(j - ig) * bs;
                    if (j > ig) v2 = -INFINITY;
                    xv[nt] = v2;
                    mloc = fmaxf(mloc, v2);
                }
                #pragma unroll
                for (int off = 1; off < 16; off <<= 1)
                    mloc = fmaxf(mloc, __shfl_xor(mloc, off));
                const float mnew = fmaxf(mrow[rt][r], mloc);
                const float mq   = (mnew == -INFINITY) ? 0.0f : mnew;
                const float alpha = __expf(mrow[rt][r] - mq);
                mrow[rt][r] = mnew;
                float ps = 0.0f;
                #pragma unroll
                for (int nt = 0; nt < 4; nt++) {
                    const float p = __expf(xv[nt] - mq);
                    ps += p;
                    pw[(rt * 16 + quad * 4 + r) * 72 + nt * 16 + l15] = f2bf_fast(p);
                }
                lrow[rt][r] = lrow[rt][r] * alpha + ps;   // per-lane partial
                #pragma unroll
                for (int nt = 0; nt < 4; nt++) O[rt][nt][r] *= alpha;
            }

        // ---- O += P V  (same-wave DS in-order; no barrier) ----
        #pragma unroll
        for (int rt = 0; rt < 2; rt++) {
            const bf16x8 pf0 = *(const bf16x8*)&pw[(rt * 16 + l15) * 72 + quad * 8];
            const bf16x8 pf1 = *(const bf16x8*)&pw[(rt * 16 + l15) * 72 + 32 + quad * 8];
            #pragma unroll
            for (int nt = 0; nt < 4; nt++) {
                O[rt][nt] = MFMA(pf0, vf[nt][0], O[rt][nt]);
                O[rt][nt] = MFMA(pf1, vf[nt][1], O[rt][nt]);
            }
        }

        if (more) {
            #pragma unroll
            for (int nt = 0; nt < 4; nt++)
                #pragma unroll
                for (int ks = 0; ks < 2; ks++) {
                    kf[nt][ks] = kf2[nt][ks];
                    vf[nt][ks] = vf2[nt][ks];
                }
        }
    }
    #undef LOADSTEP

    // ---- reduce per-lane l partials across the 16 key-lanes ----
    #pragma unroll
    for (int rt = 0; rt < 2; rt++)
        #pragma unroll
        for (int r = 0; r < 4; r++)
            #pragma unroll
            for (int off = 1; off < 16; off <<= 1)
                lrow[rt][r] += __shfl_xor(lrow[rt][r], off);

    __syncthreads();   // all waves done with pT

    // ---- publish partial state ----
    #pragma unroll
    for (int rt = 0; rt < 2; rt++)
        #pragma unroll
        for (int nt = 0; nt < 4; nt++)
            #pragma unroll
            for (int r = 0; r < 4; r++)
                Omg[w * 2048 + (rt * 16 + quad * 4 + r) * 64 + nt * 16 + l15]
                    = O[rt][nt][r];
    if (l15 == 0) {
        #pragma unroll
        for (int rt = 0; rt < 2; rt++)
            #pragma unroll
            for (int r = 0; r < 4; r++) {
                mlg[w * 64 + rt * 16 + quad * 4 + r]      = mrow[rt][r];
                mlg[w * 64 + 32 + rt * 16 + quad * 4 + r] = lrow[rt][r];
            }
    }
    __syncthreads();

    // ---- merge 4 partials, write output ----
    {
        const int row = t >> 3;          // 0..31
        const int hq  = (t & 7) << 3;    // 0..56
        float mstar = -INFINITY;
        #pragma unroll
        for (int w2 = 0; w2 < 4; w2++)
            mstar = fmaxf(mstar, mlg[w2 * 64 + row]);
        floatx4 oa0 = (floatx4)(0.0f), oa1 = (floatx4)(0.0f);
        float lsum = 0.0f;
        #pragma unroll
        for (int w2 = 0; w2 < 4; w2++) {
            const float wg = __expf(mlg[w2 * 64 + row] - mstar);
            lsum += wg * mlg[w2 * 64 + 32 + row];
            oa0 += wg * *(const floatx4*)&Omg[w2 * 2048 + row * 64 + hq];
            oa1 += wg * *(const floatx4*)&Omg[w2 * 2048 + row * 64 + hq + 4];
        }
        const float inv = 1.0f / lsum;
        *(floatx4*)&out[kb + (size_t)(q0 + row) * 64 + hq]     = oa0 * inv;
        *(floatx4*)&out[kb + (size_t)(q0 + row) * 64 + hq + 4] = oa1 * inv;
    }
}

extern "C" void kernel_launch(void* const* d_in, const int* in_sizes, int n_in,
                              void* d_out, int out_size, void* d_ws, size_t ws_size,
                              hipStream_t stream) {
    (void)in_sizes; (void)n_in; (void)out_size; (void)ws_size;
    const float* x  = (const float*)d_in[0];
    const float* Wq = (const float*)d_in[1];
    const float* Wk = (const float*)d_in[2];
    const float* Wv = (const float*)d_in[3];
    float* out = (float*)d_out;

    unsigned short* wt2 = (unsigned short*)d_ws;                // [12][32][64][8]
    unsigned short* qw  = wt2 + 196608;                         // [M][64]
    unsigned short* kw  = qw + (size_t)M_ * H_;                 // [M][64]
    unsigned short* vw  = kw + (size_t)M_ * H_;                 // [B][64][2048]

    wprep_kernel<<<96, 256, 0, stream>>>(Wq, Wk, Wv, wt2);
    qkv_kernel<<<M_ / 64, 256, 0, stream>>>(x, wt2, qw, kw, vw);
    attn_kernel<<<B_ * 64, 256, 0, stream>>>(qw, kw, vw, out);
}

// Round 8
// 140.511 us; speedup vs baseline: 1.2308x; 1.0302x over previous
//
#include <hip/hip_runtime.h>
#include <hip/hip_bf16.h>
#include <math.h>

#define B_ 8
#define T_ 2048
#define C_ 1024
#define H_ 64
#define M_ (B_*T_)   // 16384 rows

typedef __attribute__((ext_vector_type(8))) short bf16x8;
typedef __attribute__((ext_vector_type(4))) float floatx4;

// fp32 -> bf16 round-to-nearest-even (cold paths)
static __device__ __forceinline__ unsigned short f2bf(float f) {
    union { float f; unsigned u; } v; v.f = f;
    unsigned r = v.u + 0x7fffu + ((v.u >> 16) & 1u);
    return (unsigned short)(r >> 16);
}
// fp32 -> bf16 round-half-up (2 VALU) for hot paths
static __device__ __forceinline__ unsigned short f2bf_fast(float f) {
    union { float f; unsigned u; } v; v.f = f;
    return (unsigned short)((v.u + 0x8000u) >> 16);
}
// pack two fp32 -> bf16 pair [hi|lo] in 3 VALU (add, add, v_perm)
static __device__ __forceinline__ unsigned pk2h(float lo, float hi) {
    union { float f; unsigned u; } a, b; a.f = lo; b.f = hi;
    return __builtin_amdgcn_perm(b.u + 0x8000u, a.u + 0x8000u, 0x07060302u);
}
static __device__ __forceinline__ bf16x8 cvt8(float4 f0, float4 f1) {
    union { uint4 u; bf16x8 v; } r;
    r.u.x = pk2h(f0.x, f0.y); r.u.y = pk2h(f0.z, f0.w);
    r.u.z = pk2h(f1.x, f1.y); r.u.w = pk2h(f1.z, f1.w);
    return r.v;
}

#define MFMA(a,b,c) __builtin_amdgcn_mfma_f32_16x16x32_bf16((a),(b),(c),0,0,0)

// ---------------------------------------------------------------------------
// Kernel 0: W prep -> wt2 in MFMA B-fragment order.
// wt2 flat: ((tile*32 + kchunk)*64 + lane)*8; tile=0..11 (16 cols, q|k|v),
// kchunk=0..31 (32 k each); lane frag [col=l15][k=quad*8+j].
// q-columns (tiles 0..3) pre-scaled by 0.125.
// ---------------------------------------------------------------------------
__global__ __launch_bounds__(256) void wprep_kernel(
    const float* __restrict__ Wq, const float* __restrict__ Wk,
    const float* __restrict__ Wv, unsigned short* __restrict__ wt2)
{
    const int f    = blockIdx.x * 256 + threadIdx.x;  // 0..24575
    const int nt   = f >> 11;
    const int kc   = (f >> 6) & 31;
    const int lane = f & 63;
    const int l15  = lane & 15, quad = lane >> 4;
    const int col  = nt * 16 + l15;                   // 0..191
    const float* W = (col < 64) ? Wq : ((col < 128) ? Wk : Wv);
    const int   cw = col & 63;
    const float sc = (col < 64) ? 0.125f : 1.0f;
    unsigned short o[8];
    #pragma unroll
    for (int j = 0; j < 8; j++) {
        const int kk = kc * 32 + quad * 8 + j;
        o[j] = f2bf(W[(size_t)kk * 64 + cw] * sc);
    }
    *(uint4*)&wt2[(size_t)f * 8] = *(const uint4*)o;
}

// ---------------------------------------------------------------------------
// Kernel 1: QKV projection. Grid 256 x 256 thr. Block = 64 rows x 192 cols.
// x staged once/block into double-buffered LDS [64][72] bf16 with a
// DEPTH-2 register prefetch (chunk c+2 issued while chunk c computes) so
// ~32 KB/block stays in flight against HBM latency. W per-wave direct
// fragment-ordered loads, depth-1 (L2-resident).
// ---------------------------------------------------------------------------
__global__ __launch_bounds__(256) void qkv_kernel(
    const float* __restrict__ x, const unsigned short* __restrict__ wt2,
    unsigned short* __restrict__ qo, unsigned short* __restrict__ ko,
    unsigned short* __restrict__ vo)
{
    // union: xs[2][64*72] (18.4 KB) during loop; es[64][200] (25.6 KB) epilogue
    __shared__ __align__(16) unsigned short smem[64 * 200];
    #define XS_(buf) (smem + (buf) * 4608)

    const int t    = threadIdx.x;
    const int w    = t >> 6;
    const int lane = t & 63;
    const int l15  = lane & 15;
    const int quad = lane >> 4;
    const int r0   = blockIdx.x * 64;

    // staging map: row = t>>2 (0..63), groups {t&3, (t&3)+4} (8 floats each)
    const int srow = t >> 2;
    const int g0   = t & 3;
    const float* xrow = x + (size_t)(r0 + srow) * C_;

    // W pointers: wave w owns tiles w*3 .. w*3+2
    const unsigned short* wb = wt2 + (size_t)(w * 3) * 32 * 512 + lane * 8;

    floatx4 acc[4][3];
    #pragma unroll
    for (int mt = 0; mt < 4; mt++)
        #pragma unroll
        for (int nt = 0; nt < 3; nt++) acc[mt][nt] = (floatx4)(0.0f);

    float4 xA[4], xB[4];
    bf16x8 wcur[6], wnxt[6];

    // ---- preamble: issue x chunks 0,1 and W chunk 0; stage chunk 0 ----
    #pragma unroll
    for (int j = 0; j < 2; j++) {
        const int g = g0 + 4 * j;
        xA[2*j+0] = *(const float4*)(xrow + g * 8);
        xA[2*j+1] = *(const float4*)(xrow + g * 8 + 4);
        xB[2*j+0] = *(const float4*)(xrow + 64 + g * 8);
        xB[2*j+1] = *(const float4*)(xrow + 64 + g * 8 + 4);
    }
    #pragma unroll
    for (int nt = 0; nt < 3; nt++)
        #pragma unroll
        for (int ks = 0; ks < 2; ks++)
            wcur[nt * 2 + ks] = *(const bf16x8*)(wb + (size_t)(nt * 32 + ks) * 512);
    #pragma unroll
    for (int j = 0; j < 2; j++) {
        const int g = g0 + 4 * j;
        *(bf16x8*)(XS_(0) + srow * 72 + g * 8) = cvt8(xA[2*j], xA[2*j+1]);
    }
    __syncthreads();

    // step c: prefetch chunk c+2 into Xcur (freed), compute chunk c from
    // LDS(buf)+wcur, stage chunk c+1 from Xnext into LDS(buf^1), roll W.
    #define QSTEP(c, Xcur, Xnext, buf)                                         \
    {                                                                          \
        if ((c) < 14) {                                                        \
            const int k2 = ((c) + 2) * 64;                                     \
            _Pragma("unroll")                                                  \
            for (int j = 0; j < 2; j++) {                                      \
                const int g = g0 + 4 * j;                                      \
                Xcur[2*j+0] = *(const float4*)(xrow + k2 + g * 8);             \
                Xcur[2*j+1] = *(const float4*)(xrow + k2 + g * 8 + 4);         \
            }                                                                  \
        }                                                                      \
        if ((c) < 15) {                                                        \
            _Pragma("unroll")                                                  \
            for (int nt = 0; nt < 3; nt++)                                     \
                _Pragma("unroll")                                              \
                for (int ks = 0; ks < 2; ks++)                                 \
                    wnxt[nt * 2 + ks] = *(const bf16x8*)                       \
                        (wb + (size_t)(nt * 32 + 2 * ((c) + 1) + ks) * 512);   \
        }                                                                      \
        _Pragma("unroll")                                                      \
        for (int ks = 0; ks < 2; ks++) {                                       \
            bf16x8 af[4];                                                      \
            _Pragma("unroll")                                                  \
            for (int mt = 0; mt < 4; mt++)                                     \
                af[mt] = *(const bf16x8*)                                      \
                    (XS_(buf) + (mt * 16 + l15) * 72 + ks * 32 + quad * 8);    \
            _Pragma("unroll")                                                  \
            for (int mt = 0; mt < 4; mt++)                                     \
                _Pragma("unroll")                                              \
                for (int nt = 0; nt < 3; nt++)                                 \
                    acc[mt][nt] = MFMA(af[mt], wcur[nt * 2 + ks], acc[mt][nt]);\
        }                                                                      \
        if ((c) < 15) {                                                        \
            _Pragma("unroll")                                                  \
            for (int j = 0; j < 2; j++) {                                      \
                const int g = g0 + 4 * j;                                      \
                *(bf16x8*)(XS_((buf) ^ 1) + srow * 72 + g * 8)                 \
                    = cvt8(Xnext[2*j], Xnext[2*j+1]);                          \
            }                                                                  \
            _Pragma("unroll")                                                  \
            for (int i = 0; i < 6; i++) wcur[i] = wnxt[i];                     \
        }                                                                      \
        __syncthreads();                                                       \
    }

    for (int cc = 0; cc < 16; cc += 2) {
        QSTEP(cc,     xA, xB, 0)
        QSTEP(cc + 1, xB, xA, 1)
    }
    #undef QSTEP

    // ---- epilogue: repack through LDS (aliases xs; loop-end barrier done) ---
    #pragma unroll
    for (int mt = 0; mt < 4; mt++)
        #pragma unroll
        for (int nt = 0; nt < 3; nt++) {
            const int col = w * 48 + nt * 16 + l15;
            #pragma unroll
            for (int r = 0; r < 4; r++)
                smem[(mt * 16 + quad * 4 + r) * 200 + col] = f2bf(acc[mt][nt][r]);
        }
    __syncthreads();

    { // q, k: [row][64] bf16
        #pragma unroll
        for (int i = 0; i < 2; i++) {
            const int fo  = t + i * 256;      // 0..511
            const int row = fo >> 3;
            const int oct = fo & 7;
            *(uint4*)&qo[(size_t)(r0 + row) * 64 + oct * 8] =
                *(const uint4*)&smem[row * 200 + oct * 8];
            *(uint4*)&ko[(size_t)(r0 + row) * 64 + oct * 8] =
                *(const uint4*)&smem[row * 200 + 64 + oct * 8];
        }
    }
    { // v: transposed [b][h][t]
        const int h = t >> 2, ts = (t & 3) * 16;
        const int bb = r0 >> 11, tt = r0 & 2047;
        unsigned short tmp[16];
        #pragma unroll
        for (int j = 0; j < 16; j++) tmp[j] = smem[(ts + j) * 200 + 128 + h];
        #pragma unroll
        for (int j = 0; j < 2; j++)
            *(uint4*)&vo[((size_t)bb * 64 + h) * 2048 + tt + ts + j * 8] =
                *(uint4*)&tmp[j * 8];
    }
    #undef XS_
}

// ---------------------------------------------------------------------------
// Kernel 2: causal flash attention with ALiBi, bf16 MFMA.
// 256 thr (4 waves); 32-row q-tile (2 row-tiles/wave -> K/V reused 2x);
// K-range split 4 ways across waves; per-wave private softmax state + pT
// region, no per-step barriers. K prefetched one step ahead (register
// double-buffer); V loaded per-step right after QK^T (L2 slack covers it)
// -> ~60 fewer live VGPRs than the R7 full double-buffer, no spills.
// Grid 512 = 8 batches x 64 q-tiles, heavy-first.
// ---------------------------------------------------------------------------
__global__ __launch_bounds__(256, 2) void attn_kernel(
    const unsigned short* __restrict__ q,
    const unsigned short* __restrict__ k,
    const unsigned short* __restrict__ vT,
    float* __restrict__ out)
{
    // pT during loop: 4 waves x 32x72 halfs = 18432 B at offset 0.
    // merge after barrier: Omg [4][32][64] f32 = 32768 B at 0,
    //                      mlg [4][2][32]  f32 =  1024 B at 32768.
    __shared__ __align__(16) unsigned char smem[32768 + 1024];
    unsigned short* pT  = (unsigned short*)smem;
    float*          Omg = (float*)smem;
    float*          mlg = (float*)(smem + 32768);

    const int t    = threadIdx.x;
    const int w    = t >> 6;
    const int lane = t & 63;
    const int l15  = lane & 15;
    const int quad = lane >> 4;
    const int b    = blockIdx.x & 7;
    const int qt   = 63 - (blockIdx.x >> 3);   // heavy tiles first
    const int q0   = qt * 32;
    const size_t kb = (size_t)b * T_ * 64;

    // Q A-fragments for both row-tiles (scale folded into Wq)
    bf16x8 qf[2][2];
    #pragma unroll
    for (int rt = 0; rt < 2; rt++)
        #pragma unroll
        for (int ks = 0; ks < 2; ks++)
            qf[rt][ks] = *(const bf16x8*)
                &q[kb + (size_t)(q0 + rt * 16 + l15) * 64 + ks * 32 + quad * 8];

    floatx4 O[2][4];
    float mrow[2][4], lrow[2][4], igb[2][4];
    const float bs = 0.088388347648318447f;     // 2^-0.5 * 0.125
    #pragma unroll
    for (int rt = 0; rt < 2; rt++) {
        #pragma unroll
        for (int nt = 0; nt < 4; nt++) O[rt][nt] = (floatx4)(0.0f);
        #pragma unroll
        for (int r = 0; r < 4; r++) {
            mrow[rt][r] = -INFINITY; lrow[rt][r] = 0.0f;
            igb[rt][r] = (float)(q0 + rt * 16 + quad * 4 + r) * bs;
        }
    }

    const int nsteps = (q0 + 32 + 63) >> 6;
    const int ns4    = (nsteps + 3) >> 2;
    const int sBeg   = w * ns4;
    const int sEnd   = min(sBeg + ns4, nsteps);
    unsigned short* pw = pT + w * 32 * 72;

    bf16x8 kf[4][2], vf[4][2];
    #define LOADK(dK, jj0)                                                     \
        { _Pragma("unroll")                                                    \
          for (int nt = 0; nt < 4; nt++)                                       \
              _Pragma("unroll")                                                \
              for (int ks = 0; ks < 2; ks++)                                   \
                  dK[nt][ks] = *(const bf16x8*)                                \
                      &k[kb + (size_t)((jj0) + nt*16 + l15)*64 + ks*32 + quad*8]; }
    #define LOADV(dV, jj0)                                                     \
        { _Pragma("unroll")                                                    \
          for (int nt = 0; nt < 4; nt++)                                       \
              _Pragma("unroll")                                                \
              for (int ks = 0; ks < 2; ks++)                                   \
                  dV[nt][ks] = *(const bf16x8*)                                \
                      &vT[((size_t)b*64 + nt*16 + l15)*2048 + (jj0) + ks*32 + quad*8]; }

    if (sBeg < sEnd) LOADK(kf, sBeg * 64)

    for (int s = sBeg; s < sEnd; s++) {
        const int j0 = s * 64;

        // ---- S = Q K^T for both row-tiles ----
        floatx4 sc[2][4];
        #pragma unroll
        for (int rt = 0; rt < 2; rt++)
            #pragma unroll
            for (int nt = 0; nt < 4; nt++) {
                floatx4 z = (floatx4)(0.0f);
                z = MFMA(qf[rt][0], kf[nt][0], z);
                z = MFMA(qf[rt][1], kf[nt][1], z);
                sc[rt][nt] = z;
            }

        // ---- issue this step's V + next step's K under softmax ----
        LOADV(vf, j0)
        bf16x8 kf2[4][2];
        const bool more = (s + 1 < sEnd);
        if (more) LOADK(kf2, (s + 1) * 64)

        // ---- ALiBi + causal + online softmax (deferred l-reduce) ----
        const float jbase = (float)(j0 + l15) * bs;
        #pragma unroll
        for (int rt = 0; rt < 2; rt++)
            #pragma unroll
            for (int r = 0; r < 4; r++) {
                const int   ig = q0 + rt * 16 + quad * 4 + r;
                const float c0 = jbase - igb[rt][r];
                float xv[4];
                float mloc = -INFINITY;
                #pragma unroll
                for (int nt = 0; nt < 4; nt++) {
                    const int j = j0 + nt * 16 + l15;
                    float v2 = (sc[rt][nt][r] + c0) + (float)(nt * 16) * bs;
                    if (j > ig) v2 = -INFINITY;
                    xv[nt] = v2;
                    mloc = fmaxf(mloc, v2);
                }
                #pragma unroll
                for (int off = 1; off < 16; off <<= 1)
                    mloc = fmaxf(mloc, __shfl_xor(mloc, off));
                const float mnew = fmaxf(mrow[rt][r], mloc);
                const float mq   = (mnew == -INFINITY) ? 0.0f : mnew;
                const float alpha = __expf(mrow[rt][r] - mq);
                mrow[rt][r] = mnew;
                float ps = 0.0f;
                #pragma unroll
                for (int nt = 0; nt < 4; nt++) {
                    const float p = __expf(xv[nt] - mq);
                    ps += p;
                    pw[(rt * 16 + quad * 4 + r) * 72 + nt * 16 + l15] = f2bf_fast(p);
                }
                lrow[rt][r] = lrow[rt][r] * alpha + ps;   // per-lane partial
                #pragma unroll
                for (int nt = 0; nt < 4; nt++) O[rt][nt][r] *= alpha;
            }

        // ---- O += P V  (same-wave DS in-order; no barrier) ----
        #pragma unroll
        for (int rt = 0; rt < 2; rt++) {
            const bf16x8 pf0 = *(const bf16x8*)&pw[(rt * 16 + l15) * 72 + quad * 8];
            const bf16x8 pf1 = *(const bf16x8*)&pw[(rt * 16 + l15) * 72 + 32 + quad * 8];
            #pragma unroll
            for (int nt = 0; nt < 4; nt++) {
                O[rt][nt] = MFMA(pf0, vf[nt][0], O[rt][nt]);
                O[rt][nt] = MFMA(pf1, vf[nt][1], O[rt][nt]);
            }
        }

        if (more) {
            #pragma unroll
            for (int nt = 0; nt < 4; nt++)
                #pragma unroll
                for (int ks = 0; ks < 2; ks++)
                    kf[nt][ks] = kf2[nt][ks];
        }
    }
    #undef LOADK
    #undef LOADV

    // ---- reduce per-lane l partials across the 16 key-lanes ----
    #pragma unroll
    for (int rt = 0; rt < 2; rt++)
        #pragma unroll
        for (int r = 0; r < 4; r++)
            #pragma unroll
            for (int off = 1; off < 16; off <<= 1)
                lrow[rt][r] += __shfl_xor(lrow[rt][r], off);

    __syncthreads();   // all waves done with pT

    // ---- publish partial state ----
    #pragma unroll
    for (int rt = 0; rt < 2; rt++)
        #pragma unroll
        for (int nt = 0; nt < 4; nt++)
            #pragma unroll
            for (int r = 0; r < 4; r++)
                Omg[w * 2048 + (rt * 16 + quad * 4 + r) * 64 + nt * 16 + l15]
                    = O[rt][nt][r];
    if (l15 == 0) {
        #pragma unroll
        for (int rt = 0; rt < 2; rt++)
            #pragma unroll
            for (int r = 0; r < 4; r++) {
                mlg[w * 64 + rt * 16 + quad * 4 + r]      = mrow[rt][r];
                mlg[w * 64 + 32 + rt * 16 + quad * 4 + r] = lrow[rt][r];
            }
    }
    __syncthreads();

    // ---- merge 4 partials, write output ----
    {
        const int row = t >> 3;          // 0..31
        const int hq  = (t & 7) << 3;    // 0..56
        float mstar = -INFINITY;
        #pragma unroll
        for (int w2 = 0; w2 < 4; w2++)
            mstar = fmaxf(mstar, mlg[w2 * 64 + row]);
        floatx4 oa0 = (floatx4)(0.0f), oa1 = (floatx4)(0.0f);
        float lsum = 0.0f;
        #pragma unroll
        for (int w2 = 0; w2 < 4; w2++) {
            const float wg = __expf(mlg[w2 * 64 + row] - mstar);
            lsum += wg * mlg[w2 * 64 + 32 + row];
            oa0 += wg * *(const floatx4*)&Omg[w2 * 2048 + row * 64 + hq];
            oa1 += wg * *(const floatx4*)&Omg[w2 * 2048 + row * 64 + hq + 4];
        }
        const float inv = 1.0f / lsum;
        *(floatx4*)&out[kb + (size_t)(q0 + row) * 64 + hq]     = oa0 * inv;
        *(floatx4*)&out[kb + (size_t)(q0 + row) * 64 + hq + 4] = oa1 * inv;
    }
}

extern "C" void kernel_launch(void* const* d_in, const int* in_sizes, int n_in,
                              void* d_out, int out_size, void* d_ws, size_t ws_size,
                              hipStream_t stream) {
    (void)in_sizes; (void)n_in; (void)out_size; (void)ws_size;
    const float* x  = (const float*)d_in[0];
    const float* Wq = (const float*)d_in[1];
    const float* Wk = (const float*)d_in[2];
    const float* Wv = (const float*)d_in[3];
    float* out = (float*)d_out;

    unsigned short* wt2 = (unsigned short*)d_ws;                // [12][32][64][8]
    unsigned short* qw  = wt2 + 196608;                         // [M][64]
    unsigned short* kw  = qw + (size_t)M_ * H_;                 // [M][64]
    unsigned short* vw  = kw + (size_t)M_ * H_;                 // [B][64][2048]

    wprep_kernel<<<96, 256, 0, stream>>>(Wq, Wk, Wv, wt2);
    qkv_kernel<<<M_ / 64, 256, 0, stream>>>(x, wt2, qw, kw, vw);
    attn_kernel<<<B_ * 64, 256, 0, stream>>>(qw, kw, vw, out);
}